// Round 1
// baseline (250.810 us; speedup 1.0000x reference)
//
#include <hip/hip_runtime.h>
#include <cstdint>
#include <cstddef>

#define NTOK 16384
#define FDIM 32
#define HDIM 128

typedef __attribute__((ext_vector_type(8))) short short8;     // bf16x8 MFMA frag
typedef __attribute__((ext_vector_type(4))) float float4v;
typedef __attribute__((ext_vector_type(4))) unsigned int uint4v;

__device__ __forceinline__ float elu_f(float x)  { return x > 0.f ? x : __expf(x) - 1.f; }
__device__ __forceinline__ float sigm_f(float x) { return 1.f / (1.f + __expf(-x)); }

// fp32 -> bf16 round-to-nearest-even, bits in low 16
__device__ __forceinline__ unsigned int f2bf(float f) {
  unsigned int u = __float_as_uint(f);
  u += 0x7FFFu + ((u >> 16) & 1u);
  return u >> 16;
}

// ---------------------------------------------------------------------------
// Kernel 1: (a) blocks [0,128): precompute fcomb = fw2 @ fglu_w in bf16,
//               stored directly in MFMA B-fragment order, with v/gate column
//               interleave; plus combined bias bcomb (fp32, permuted cols).
//           (b) blocks [128, 128+NTOK/4): weight-GRN -> softmax weights,
//               one token per wave.
// col' mapping: ct in [0,16): w=ct>>2, hp=(ct>>1)&1, type=ct&1
//               h = w*32 + hp*16 + c  (c = col within tile)
//               o2(original) = type*128 + h
// ---------------------------------------------------------------------------
__global__ __launch_bounds__(256) void k_pw(
    const float* __restrict__ x,
    const float* __restrict__ fw2, const float* __restrict__ fb2,
    const float* __restrict__ fglu_w, const float* __restrict__ fglu_b,
    const float* __restrict__ ww1, const float* __restrict__ wb1,
    const float* __restrict__ ww2, const float* __restrict__ wb2,
    const float* __restrict__ wglu_w, const float* __restrict__ wglu_b,
    const float* __restrict__ wln_g, const float* __restrict__ wln_b,
    unsigned short* __restrict__ bfrag, float* __restrict__ bcomb,
    float* __restrict__ wout)
{
  __shared__ __align__(16) float smem[4096];
  const int tid = threadIdx.x;

  if (blockIdx.x < 128) {
    // ---------------- fcomb precompute ----------------
    const int f  = blockIdx.x >> 2;
    const int ks = blockIdx.x & 3;
    // stage fw2[f][ks*32 .. ks*32+32)[:] (32x128 f32) into LDS, row-major
    const float* src = fw2 + ((size_t)f * 128 + ks * 32) * 128;
    for (int i = 0; i < 4; ++i) {
      int vi = tid + i * 256;
      *(float4v*)&smem[vi * 4] = *(const float4v*)&src[vi * 4];
    }
    __syncthreads();

    const int o2 = tid;          // original output column 0..255
    float acc[32];
#pragma unroll
    for (int kk = 0; kk < 32; ++kk) acc[kk] = 0.f;
    float bacc = 0.f;

    for (int o = 0; o < 128; o += 4) {
      float gv0 = fglu_w[((size_t)f * 128 + o + 0) * 256 + o2];
      float gv1 = fglu_w[((size_t)f * 128 + o + 1) * 256 + o2];
      float gv2 = fglu_w[((size_t)f * 128 + o + 2) * 256 + o2];
      float gv3 = fglu_w[((size_t)f * 128 + o + 3) * 256 + o2];
      bacc += fb2[f * 128 + o + 0] * gv0 + fb2[f * 128 + o + 1] * gv1
            + fb2[f * 128 + o + 2] * gv2 + fb2[f * 128 + o + 3] * gv3;
#pragma unroll
      for (int kk = 0; kk < 32; ++kk) {
        float4v a4 = *(const float4v*)&smem[kk * 128 + o];
        acc[kk] += a4[0] * gv0 + a4[1] * gv1 + a4[2] * gv2 + a4[3] * gv3;
      }
    }

    const int type = o2 >> 7;
    const int hq   = o2 & 127;
    const int wv   = hq >> 5;
    const int hp   = (hq >> 4) & 1;
    const int cc   = hq & 15;
    const int ct   = wv * 4 + hp * 2 + type;

#pragma unroll
    for (int gg = 0; gg < 4; ++gg) {
      uint4v pk;
      unsigned int u0 = f2bf(acc[gg * 8 + 0]), u1 = f2bf(acc[gg * 8 + 1]);
      unsigned int u2 = f2bf(acc[gg * 8 + 2]), u3 = f2bf(acc[gg * 8 + 3]);
      unsigned int u4 = f2bf(acc[gg * 8 + 4]), u5 = f2bf(acc[gg * 8 + 5]);
      unsigned int u6 = f2bf(acc[gg * 8 + 6]), u7 = f2bf(acc[gg * 8 + 7]);
      pk[0] = u0 | (u1 << 16);
      pk[1] = u2 | (u3 << 16);
      pk[2] = u4 | (u5 << 16);
      pk[3] = u6 | (u7 << 16);
      size_t off = ((((size_t)f * 16 + ct) * 4 + ks) * 64 + (gg * 16 + cc)) * 8;
      *(uint4v*)(bfrag + off) = pk;
    }
    if (ks == 0)
      bcomb[f * 256 + ct * 16 + cc] = bacc + fglu_b[f * 256 + o2];

  } else {
    // ---------------- weight GRN + softmax, one token per wave ----------------
    const int bid = blockIdx.x - 128;
    const int wv  = tid >> 6;
    const int l   = tid & 63;
    const int t   = bid * 4 + wv;
    float* S = smem + wv * 256;   // per-wave scratch: x[0..32) wh[32..160) wh2[160..192)

    float xv = x[(size_t)t * 32 + (l & 31)];
    if (l < 32) S[l] = xv;
    float a0 = wb1[l], a1 = wb1[l + 64];
    __syncthreads();
    for (int f2 = 0; f2 < 32; ++f2) {
      float xf = S[f2];
      a0 = fmaf(xf, ww1[f2 * 128 + l], a0);
      a1 = fmaf(xf, ww1[f2 * 128 + l + 64], a1);
    }
    a0 = elu_f(a0); a1 = elu_f(a1);
    S[32 + l] = a0; S[32 + l + 64] = a1;
    __syncthreads();

    const int o    = l & 31;
    const int half = l >> 5;
    float b = 0.f;
    for (int hh = 0; hh < 64; ++hh)
      b = fmaf(S[32 + half * 64 + hh], ww2[(half * 64 + hh) * 32 + o], b);
    b += __shfl_xor(b, 32);
    b += wb2[o];
    S[160 + o] = b;
    __syncthreads();

    float g = wglu_b[l];
    for (int o2i = 0; o2i < 32; ++o2i)
      g = fmaf(S[160 + o2i], wglu_w[o2i * 64 + l], g);

    float gate = __shfl_xor(g, 32);               // lanes<32: wg[l+32]
    float y = g * sigm_f(gate) + xv;              // GLU + identity skip
    float s = y;
    s += __shfl_xor(s, 1); s += __shfl_xor(s, 2); s += __shfl_xor(s, 4);
    s += __shfl_xor(s, 8); s += __shfl_xor(s, 16);
    float mean = s * (1.f / 32.f);
    float d = y - mean;
    float ss = d * d;
    ss += __shfl_xor(ss, 1); ss += __shfl_xor(ss, 2); ss += __shfl_xor(ss, 4);
    ss += __shfl_xor(ss, 8); ss += __shfl_xor(ss, 16);
    float rstd = rsqrtf(ss * (1.f / 32.f) + 1e-5f);
    const int cc = l & 31;
    float ln = d * rstd * wln_g[cc] + wln_b[cc];
    float mx = ln;
    mx = fmaxf(mx, __shfl_xor(mx, 1));  mx = fmaxf(mx, __shfl_xor(mx, 2));
    mx = fmaxf(mx, __shfl_xor(mx, 4));  mx = fmaxf(mx, __shfl_xor(mx, 8));
    mx = fmaxf(mx, __shfl_xor(mx, 16));
    float e = __expf(ln - mx);
    float se = e;
    se += __shfl_xor(se, 1); se += __shfl_xor(se, 2); se += __shfl_xor(se, 4);
    se += __shfl_xor(se, 8); se += __shfl_xor(se, 16);
    if (l < 32) wout[(size_t)t * 32 + l] = e / se;
  }
}

// ---------------------------------------------------------------------------
// Kernel 2: main fused per-feature GRN + LN + weighted combine.
// Block = 256 threads (4 waves), 64 tokens. Wave w owns output cols
// [w*64, w*64+64) of the 256 interleaved v/gate columns -> h in [w*32,w*32+32).
// ---------------------------------------------------------------------------
__global__ __launch_bounds__(256, 1) void k_main(
    const float* __restrict__ x,
    const float* __restrict__ fw1, const float* __restrict__ fb1,
    const float* __restrict__ fskip, const float* __restrict__ flng,
    const float* __restrict__ flnb,
    const unsigned short* __restrict__ bfrag, const float* __restrict__ bcomb,
    const float* __restrict__ wts, float* __restrict__ out)
{
  __shared__ __align__(16) unsigned short a_lds[64 * 128];  // swizzled bf16 h1
  __shared__ __align__(16) float x_lds[FDIM * 64];          // [f][t]
  __shared__ __align__(16) float w_lds[FDIM * 64];          // [f][t]
  __shared__ __align__(16) float red_lds[64 * 8];           // [row][wave*2 + {s,ss}]

  const int tid = threadIdx.x;
  const int w   = tid >> 6;
  const int l   = tid & 63;
  const int c   = l & 15;
  const int g16 = l >> 4;
  const int t0  = blockIdx.x * 64;

  // stage x tile and weights tile (transposed to [f][t])
  for (int i = 0; i < 2; ++i) {
    int vbase = (tid + i * 256) * 4;
    float4v xv  = *(const float4v*)(x   + (size_t)t0 * FDIM + vbase);
    float4v wv4 = *(const float4v*)(wts + (size_t)t0 * FDIM + vbase);
#pragma unroll
    for (int e = 0; e < 4; ++e) {
      int flat = vbase + e;
      x_lds[(flat & 31) * 64 + (flat >> 5)] = xv[e];
      w_lds[(flat & 31) * 64 + (flat >> 5)] = wv4[e];
    }
  }

  float out_acc[2][4][4];
#pragma unroll
  for (int hp = 0; hp < 2; ++hp)
#pragma unroll
    for (int rt = 0; rt < 4; ++rt)
#pragma unroll
      for (int i = 0; i < 4; ++i) out_acc[hp][rt][i] = 0.f;

  __syncthreads();

  for (int f = 0; f < FDIM; ++f) {
    // ---- h1 = ELU(x_f * fw1 + fb1) -> a_lds (bf16, XOR-swizzled rows) ----
#pragma unroll
    for (int i = 0; i < 4; ++i) {
      int cid = tid + i * 256;
      int t   = cid >> 4;
      int k0  = (cid & 15) * 8;
      float xf = x_lds[f * 64 + t];
      float4v w1a = *(const float4v*)(fw1 + f * HDIM + k0);
      float4v w1b = *(const float4v*)(fw1 + f * HDIM + k0 + 4);
      float4v b1a = *(const float4v*)(fb1 + f * HDIM + k0);
      float4v b1b = *(const float4v*)(fb1 + f * HDIM + k0 + 4);
      unsigned int u0 = f2bf(elu_f(fmaf(xf, w1a[0], b1a[0])));
      unsigned int u1 = f2bf(elu_f(fmaf(xf, w1a[1], b1a[1])));
      unsigned int u2 = f2bf(elu_f(fmaf(xf, w1a[2], b1a[2])));
      unsigned int u3 = f2bf(elu_f(fmaf(xf, w1a[3], b1a[3])));
      unsigned int u4 = f2bf(elu_f(fmaf(xf, w1b[0], b1b[0])));
      unsigned int u5 = f2bf(elu_f(fmaf(xf, w1b[1], b1b[1])));
      unsigned int u6 = f2bf(elu_f(fmaf(xf, w1b[2], b1b[2])));
      unsigned int u7 = f2bf(elu_f(fmaf(xf, w1b[3], b1b[3])));
      uint4v pk;
      pk[0] = u0 | (u1 << 16); pk[1] = u2 | (u3 << 16);
      pk[2] = u4 | (u5 << 16); pk[3] = u6 | (u7 << 16);
      int byte = t * 256 + k0 * 2;
      byte ^= (t & 7) << 4;
      *(uint4v*)((char*)a_lds + byte) = pk;
    }
    __syncthreads();   // B1: a_lds ready

    // ---- B fragments direct from global (L2-resident, fragment-ordered) ----
    short8 bfr[4][4];
    {
      const unsigned short* bb = bfrag + (size_t)(f * 16 + w * 4) * 2048;
#pragma unroll
      for (int ct = 0; ct < 4; ++ct)
#pragma unroll
        for (int ks = 0; ks < 4; ++ks)
          bfr[ct][ks] = *(const short8*)(bb + ct * 2048 + ks * 512 + l * 8);
    }

    // ---- GEMM: 64 MFMAs per wave ----
    float4v acc[4][4];   // [ct'][rt]
#pragma unroll
    for (int ct = 0; ct < 4; ++ct)
#pragma unroll
      for (int rt = 0; rt < 4; ++rt)
        acc[ct][rt] = (float4v){0.f, 0.f, 0.f, 0.f};

#pragma unroll
    for (int ks = 0; ks < 4; ++ks) {
      short8 afr[4];
#pragma unroll
      for (int rt = 0; rt < 4; ++rt) {
        int row  = rt * 16 + c;
        int byte = row * 256 + (ks * 32 + g16 * 8) * 2;
        byte ^= (row & 7) << 4;
        afr[rt] = *(const short8*)((const char*)a_lds + byte);
      }
#pragma unroll
      for (int ct = 0; ct < 4; ++ct)
#pragma unroll
        for (int rt = 0; rt < 4; ++rt)
          acc[ct][rt] = __builtin_amdgcn_mfma_f32_16x16x32_bf16(
              afr[rt], bfr[ct][ks], acc[ct][rt], 0, 0, 0);
    }

    // ---- epilogue: bias, GLU, skip, LN partials ----
    float bc0 = bcomb[f * 256 + (w * 4 + 0) * 16 + c];
    float bc1 = bcomb[f * 256 + (w * 4 + 1) * 16 + c];
    float bc2 = bcomb[f * 256 + (w * 4 + 2) * 16 + c];
    float bc3 = bcomb[f * 256 + (w * 4 + 3) * 16 + c];
    float fs[2], lg[2], lb[2];
#pragma unroll
    for (int hp = 0; hp < 2; ++hp) {
      int h = w * 32 + hp * 16 + c;
      fs[hp] = fskip[f * HDIM + h];
      lg[hp] = flng[f * HDIM + h];
      lb[hp] = flnb[f * HDIM + h];
    }

    float yv[2][4][4];
    float ps[4][4], pss[4][4];
#pragma unroll
    for (int rt = 0; rt < 4; ++rt) {
      float4v x4 = *(const float4v*)&x_lds[f * 64 + rt * 16 + g16 * 4];
#pragma unroll
      for (int i = 0; i < 4; ++i) {
        float v0 = acc[0][rt][i] + bc0;
        float g0 = acc[1][rt][i] + bc1;
        float v1 = acc[2][rt][i] + bc2;
        float g1 = acc[3][rt][i] + bc3;
        float y0 = fmaf(x4[i], fs[0], v0 * sigm_f(g0));
        float y1 = fmaf(x4[i], fs[1], v1 * sigm_f(g1));
        yv[0][rt][i] = y0; yv[1][rt][i] = y1;
        ps[rt][i]  = y0 + y1;
        pss[rt][i] = y0 * y0 + y1 * y1;
      }
    }
    // reduce over the 16 lanes of each row-group
#pragma unroll
    for (int rt = 0; rt < 4; ++rt)
#pragma unroll
      for (int i = 0; i < 4; ++i) {
        float a = ps[rt][i], b2 = pss[rt][i];
        a += __shfl_xor(a, 1);  b2 += __shfl_xor(b2, 1);
        a += __shfl_xor(a, 2);  b2 += __shfl_xor(b2, 2);
        a += __shfl_xor(a, 4);  b2 += __shfl_xor(b2, 4);
        a += __shfl_xor(a, 8);  b2 += __shfl_xor(b2, 8);
        ps[rt][i] = a; pss[rt][i] = b2;
      }
    if (c == 0) {
#pragma unroll
      for (int rt = 0; rt < 4; ++rt)
#pragma unroll
        for (int i = 0; i < 4; ++i) {
          int row = rt * 16 + g16 * 4 + i;
          red_lds[row * 8 + w * 2]     = ps[rt][i];
          red_lds[row * 8 + w * 2 + 1] = pss[rt][i];
        }
    }
    __syncthreads();   // B2: red_lds ready

    // ---- LN finalize + weighted accumulate ----
#pragma unroll
    for (int rt = 0; rt < 4; ++rt) {
      float4v w4 = *(const float4v*)&w_lds[f * 64 + rt * 16 + g16 * 4];
#pragma unroll
      for (int i = 0; i < 4; ++i) {
        int row = rt * 16 + g16 * 4 + i;
        float4v r0 = *(const float4v*)&red_lds[row * 8];
        float4v r1 = *(const float4v*)&red_lds[row * 8 + 4];
        float s  = r0[0] + r0[2] + r1[0] + r1[2];
        float ss = r0[1] + r0[3] + r1[1] + r1[3];
        float mean = s * (1.f / 128.f);
        float var  = ss * (1.f / 128.f) - mean * mean;
        float rstd = rsqrtf(var + 1e-5f);
        float wt = w4[i];
#pragma unroll
        for (int hp = 0; hp < 2; ++hp) {
          float o2 = (yv[hp][rt][i] - mean) * rstd * lg[hp] + lb[hp];
          out_acc[hp][rt][i] = fmaf(wt, o2, out_acc[hp][rt][i]);
        }
      }
    }
  }

  // ---- store ----
#pragma unroll
  for (int rt = 0; rt < 4; ++rt)
#pragma unroll
    for (int i = 0; i < 4; ++i) {
      int row = t0 + rt * 16 + g16 * 4 + i;
#pragma unroll
      for (int hp = 0; hp < 2; ++hp) {
        int h = w * 32 + hp * 16 + c;
        out[(size_t)row * HDIM + h] = out_acc[hp][rt][i];
      }
    }
}

extern "C" void kernel_launch(void* const* d_in, const int* in_sizes, int n_in,
                              void* d_out, int out_size, void* d_ws, size_t ws_size,
                              hipStream_t stream) {
  const float* x      = (const float*)d_in[0];
  const float* fw1    = (const float*)d_in[1];
  const float* fb1    = (const float*)d_in[2];
  const float* fw2    = (const float*)d_in[3];
  const float* fb2    = (const float*)d_in[4];
  const float* fglu_w = (const float*)d_in[5];
  const float* fglu_b = (const float*)d_in[6];
  const float* fskip  = (const float*)d_in[7];
  const float* fln_g  = (const float*)d_in[8];
  const float* fln_b  = (const float*)d_in[9];
  const float* ww1    = (const float*)d_in[10];
  const float* wb1    = (const float*)d_in[11];
  const float* ww2    = (const float*)d_in[12];
  const float* wb2    = (const float*)d_in[13];
  const float* wglu_w = (const float*)d_in[14];
  const float* wglu_b = (const float*)d_in[15];
  const float* wln_g  = (const float*)d_in[16];
  const float* wln_b  = (const float*)d_in[17];

  float* outp = (float*)d_out;
  float* wout = outp + (size_t)NTOK * HDIM;

  unsigned short* bfrag = (unsigned short*)d_ws;                 // 2 MiB bf16
  float* bcomb = (float*)((char*)d_ws + (size_t)2 * 1024 * 1024); // 32 KiB f32

  k_pw<<<dim3(128 + NTOK / 4), dim3(256), 0, stream>>>(
      x, fw2, fb2, fglu_w, fglu_b, ww1, wb1, ww2, wb2,
      wglu_w, wglu_b, wln_g, wln_b, bfrag, bcomb, wout);
  k_main<<<dim3(NTOK / 64), dim3(256), 0, stream>>>(
      x, fw1, fb1, fskip, fln_g, fln_b, bfrag, bcomb, wout, outp);
}

// Round 2
// 172.796 us; speedup vs baseline: 1.4515x; 1.4515x over previous
//
#include <hip/hip_runtime.h>
#include <cstdint>
#include <cstddef>

#define NTOK 16384
#define FDIM 32
#define HDIM 128
#define TOKB 32

typedef __attribute__((ext_vector_type(8))) short short8;     // bf16x8 MFMA frag
typedef __attribute__((ext_vector_type(4))) float float4v;
typedef __attribute__((ext_vector_type(2))) float float2v;
typedef __attribute__((ext_vector_type(4))) unsigned int uint4v;

__device__ __forceinline__ float elu_f(float x)  { return x > 0.f ? x : __expf(x) - 1.f; }
__device__ __forceinline__ float sigm_f(float x) { return 1.f / (1.f + __expf(-x)); }

// fp32 -> bf16 round-to-nearest-even, bits in low 16
__device__ __forceinline__ unsigned int f2bf(float f) {
  unsigned int u = __float_as_uint(f);
  u += 0x7FFFu + ((u >> 16) & 1u);
  return u >> 16;
}

// DPP-based add: x + lane-permuted(x). VALU-only, no DS pipe.
template<int CTRL>
__device__ __forceinline__ float dpp_add(float x) {
  int t = __builtin_amdgcn_update_dpp(0, __float_as_int(x), CTRL, 0xF, 0xF, true);
  return x + __int_as_float(t);
}
// full 16-lane sum (all 16 lanes of the row get the total)
__device__ __forceinline__ float r16sum(float x) {
  x = dpp_add<0xB1>(x);    // quad_perm [1,0,3,2]  (xor 1)
  x = dpp_add<0x4E>(x);    // quad_perm [2,3,0,1]  (xor 2)
  x = dpp_add<0x124>(x);   // row_ror:4
  x = dpp_add<0x128>(x);   // row_ror:8
  return x;
}

// ---------------------------------------------------------------------------
// Kernel 1 (unchanged from R1): fcomb precompute + weight-GRN/softmax.
// ---------------------------------------------------------------------------
__global__ __launch_bounds__(256) void k_pw(
    const float* __restrict__ x,
    const float* __restrict__ fw2, const float* __restrict__ fb2,
    const float* __restrict__ fglu_w, const float* __restrict__ fglu_b,
    const float* __restrict__ ww1, const float* __restrict__ wb1,
    const float* __restrict__ ww2, const float* __restrict__ wb2,
    const float* __restrict__ wglu_w, const float* __restrict__ wglu_b,
    const float* __restrict__ wln_g, const float* __restrict__ wln_b,
    unsigned short* __restrict__ bfrag, float* __restrict__ bcomb,
    float* __restrict__ wout)
{
  __shared__ __align__(16) float smem[4096];
  const int tid = threadIdx.x;

  if (blockIdx.x < 128) {
    const int f  = blockIdx.x >> 2;
    const int ks = blockIdx.x & 3;
    const float* src = fw2 + ((size_t)f * 128 + ks * 32) * 128;
    for (int i = 0; i < 4; ++i) {
      int vi = tid + i * 256;
      *(float4v*)&smem[vi * 4] = *(const float4v*)&src[vi * 4];
    }
    __syncthreads();

    const int o2 = tid;
    float acc[32];
#pragma unroll
    for (int kk = 0; kk < 32; ++kk) acc[kk] = 0.f;
    float bacc = 0.f;

    for (int o = 0; o < 128; o += 4) {
      float gv0 = fglu_w[((size_t)f * 128 + o + 0) * 256 + o2];
      float gv1 = fglu_w[((size_t)f * 128 + o + 1) * 256 + o2];
      float gv2 = fglu_w[((size_t)f * 128 + o + 2) * 256 + o2];
      float gv3 = fglu_w[((size_t)f * 128 + o + 3) * 256 + o2];
      bacc += fb2[f * 128 + o + 0] * gv0 + fb2[f * 128 + o + 1] * gv1
            + fb2[f * 128 + o + 2] * gv2 + fb2[f * 128 + o + 3] * gv3;
#pragma unroll
      for (int kk = 0; kk < 32; ++kk) {
        float4v a4 = *(const float4v*)&smem[kk * 128 + o];
        acc[kk] += a4[0] * gv0 + a4[1] * gv1 + a4[2] * gv2 + a4[3] * gv3;
      }
    }

    const int type = o2 >> 7;
    const int hq   = o2 & 127;
    const int wv   = hq >> 5;
    const int hp   = (hq >> 4) & 1;
    const int cc   = hq & 15;
    const int ct   = wv * 4 + hp * 2 + type;

#pragma unroll
    for (int gg = 0; gg < 4; ++gg) {
      uint4v pk;
      unsigned int u0 = f2bf(acc[gg * 8 + 0]), u1 = f2bf(acc[gg * 8 + 1]);
      unsigned int u2 = f2bf(acc[gg * 8 + 2]), u3 = f2bf(acc[gg * 8 + 3]);
      unsigned int u4 = f2bf(acc[gg * 8 + 4]), u5 = f2bf(acc[gg * 8 + 5]);
      unsigned int u6 = f2bf(acc[gg * 8 + 6]), u7 = f2bf(acc[gg * 8 + 7]);
      pk[0] = u0 | (u1 << 16);
      pk[1] = u2 | (u3 << 16);
      pk[2] = u4 | (u5 << 16);
      pk[3] = u6 | (u7 << 16);
      size_t off = ((((size_t)f * 16 + ct) * 4 + ks) * 64 + (gg * 16 + cc)) * 8;
      *(uint4v*)(bfrag + off) = pk;
    }
    if (ks == 0)
      bcomb[f * 256 + ct * 16 + cc] = bacc + fglu_b[f * 256 + o2];

  } else {
    const int bid = blockIdx.x - 128;
    const int wv  = tid >> 6;
    const int l   = tid & 63;
    const int t   = bid * 4 + wv;
    float* S = smem + wv * 256;

    float xv = x[(size_t)t * 32 + (l & 31)];
    if (l < 32) S[l] = xv;
    float a0 = wb1[l], a1 = wb1[l + 64];
    __syncthreads();
    for (int f2 = 0; f2 < 32; ++f2) {
      float xf = S[f2];
      a0 = fmaf(xf, ww1[f2 * 128 + l], a0);
      a1 = fmaf(xf, ww1[f2 * 128 + l + 64], a1);
    }
    a0 = elu_f(a0); a1 = elu_f(a1);
    S[32 + l] = a0; S[32 + l + 64] = a1;
    __syncthreads();

    const int o    = l & 31;
    const int half = l >> 5;
    float b = 0.f;
    for (int hh = 0; hh < 64; ++hh)
      b = fmaf(S[32 + half * 64 + hh], ww2[(half * 64 + hh) * 32 + o], b);
    b += __shfl_xor(b, 32);
    b += wb2[o];
    S[160 + o] = b;
    __syncthreads();

    float g = wglu_b[l];
    for (int o2i = 0; o2i < 32; ++o2i)
      g = fmaf(S[160 + o2i], wglu_w[o2i * 64 + l], g);

    float gate = __shfl_xor(g, 32);
    float y = g * sigm_f(gate) + xv;
    float s = y;
    s += __shfl_xor(s, 1); s += __shfl_xor(s, 2); s += __shfl_xor(s, 4);
    s += __shfl_xor(s, 8); s += __shfl_xor(s, 16);
    float mean = s * (1.f / 32.f);
    float d = y - mean;
    float ss = d * d;
    ss += __shfl_xor(ss, 1); ss += __shfl_xor(ss, 2); ss += __shfl_xor(ss, 4);
    ss += __shfl_xor(ss, 8); ss += __shfl_xor(ss, 16);
    float rstd = rsqrtf(ss * (1.f / 32.f) + 1e-5f);
    const int cc = l & 31;
    float ln = d * rstd * wln_g[cc] + wln_b[cc];
    float mx = ln;
    mx = fmaxf(mx, __shfl_xor(mx, 1));  mx = fmaxf(mx, __shfl_xor(mx, 2));
    mx = fmaxf(mx, __shfl_xor(mx, 4));  mx = fmaxf(mx, __shfl_xor(mx, 8));
    mx = fmaxf(mx, __shfl_xor(mx, 16));
    float e = __expf(ln - mx);
    float se = e;
    se += __shfl_xor(se, 1); se += __shfl_xor(se, 2); se += __shfl_xor(se, 4);
    se += __shfl_xor(se, 8); se += __shfl_xor(se, 16);
    if (l < 32) wout[(size_t)t * 32 + l] = e / se;
  }
}

// ---------------------------------------------------------------------------
// Kernel 2 v2: 512 threads (8 waves), 32 tokens/block, 512 blocks.
// Wave w owns the (v,gate) ct-pair for h in [ (w>>1)*32+(w&1)*16, +16 ).
// Per wave per feature: 16 MFMA (2ct x 2rt x 4ks). LN reduce: DPP 16-lane
// sum + ds_add_f32 cross-wave into double-buffered sred.
// ---------------------------------------------------------------------------
__global__ __launch_bounds__(512, 4) void k_main(
    const float* __restrict__ x,
    const float* __restrict__ fw1, const float* __restrict__ fb1,
    const float* __restrict__ fskip, const float* __restrict__ flng,
    const float* __restrict__ flnb,
    const unsigned short* __restrict__ bfrag, const float* __restrict__ bcomb,
    const float* __restrict__ wts, float* __restrict__ out)
{
  __shared__ __align__(16) unsigned short a_lds[TOKB * 128];  // 8 KB swizzled bf16
  __shared__ __align__(16) float x_lds[FDIM * TOKB];          // [f][t] 4 KB
  __shared__ __align__(16) float w_lds[FDIM * TOKB];          // [f][t] 4 KB
  __shared__ __align__(16) float sred[2][2][TOKB];            // [buf][{s,ss}][row]

  const int tid = threadIdx.x;
  const int w   = tid >> 6;
  const int l   = tid & 63;
  const int c   = l & 15;
  const int g16 = l >> 4;
  const int t0  = blockIdx.x * TOKB;
  const int hb  = (w >> 1) * 32 + (w & 1) * 16;   // h-col base for this wave
  const int ctb = (w >> 1) * 4 + (w & 1) * 2;     // ct' base (v at +0, gate at +1)

  // stage x and weights tiles, transposed to [f][t]
  {
    float2v xv = *(const float2v*)(x   + (size_t)t0 * FDIM + tid * 2);
    float2v wv = *(const float2v*)(wts + (size_t)t0 * FDIM + tid * 2);
#pragma unroll
    for (int e = 0; e < 2; ++e) {
      int flat = tid * 2 + e;
      int tt = flat >> 5, ff = flat & 31;
      x_lds[ff * TOKB + tt] = xv[e];
      w_lds[ff * TOKB + tt] = wv[e];
    }
    if (tid < 64) sred[0][tid >> 5][tid & 31] = 0.f;
  }

  float out_acc[2][4];
#pragma unroll
  for (int rt = 0; rt < 2; ++rt)
#pragma unroll
    for (int i = 0; i < 4; ++i) out_acc[rt][i] = 0.f;

  __syncthreads();

#pragma unroll 1
  for (int f = 0; f < FDIM; ++f) {
    // ---- h1 = ELU(x_f * fw1 + fb1) -> a_lds (bf16, XOR-swizzled) ----
    {
      int t  = tid >> 4;
      int k0 = (tid & 15) * 8;
      float xf = x_lds[f * TOKB + t];
      float4v w1a = *(const float4v*)(fw1 + f * HDIM + k0);
      float4v w1b = *(const float4v*)(fw1 + f * HDIM + k0 + 4);
      float4v b1a = *(const float4v*)(fb1 + f * HDIM + k0);
      float4v b1b = *(const float4v*)(fb1 + f * HDIM + k0 + 4);
      unsigned int u0 = f2bf(elu_f(fmaf(xf, w1a[0], b1a[0])));
      unsigned int u1 = f2bf(elu_f(fmaf(xf, w1a[1], b1a[1])));
      unsigned int u2 = f2bf(elu_f(fmaf(xf, w1a[2], b1a[2])));
      unsigned int u3 = f2bf(elu_f(fmaf(xf, w1a[3], b1a[3])));
      unsigned int u4 = f2bf(elu_f(fmaf(xf, w1b[0], b1b[0])));
      unsigned int u5 = f2bf(elu_f(fmaf(xf, w1b[1], b1b[1])));
      unsigned int u6 = f2bf(elu_f(fmaf(xf, w1b[2], b1b[2])));
      unsigned int u7 = f2bf(elu_f(fmaf(xf, w1b[3], b1b[3])));
      uint4v pk;
      pk[0] = u0 | (u1 << 16); pk[1] = u2 | (u3 << 16);
      pk[2] = u4 | (u5 << 16); pk[3] = u6 | (u7 << 16);
      int byte = t * 256 + k0 * 2;
      byte ^= (t & 7) << 4;
      *(uint4v*)((char*)a_lds + byte) = pk;
    }

    // ---- B fragments + per-feature scalars: issue BEFORE barrier (L2 latency
    //      hides under the barrier wait; no LDS dependency) ----
    short8 bfr[2][4];
    {
      const unsigned short* bb = bfrag + (size_t)(f * 16 + ctb) * 2048;
#pragma unroll
      for (int ct2 = 0; ct2 < 2; ++ct2)
#pragma unroll
        for (int ks = 0; ks < 4; ++ks)
          bfr[ct2][ks] = *(const short8*)(bb + ct2 * 2048 + ks * 512 + l * 8);
    }
    float bc0 = bcomb[f * 256 + ctb * 16 + c];
    float bc1 = bcomb[f * 256 + (ctb + 1) * 16 + c];
    const int hcol = hb + c;
    float fsk = fskip[f * HDIM + hcol];
    float lgm = flng[f * HDIM + hcol];
    float lbt = flnb[f * HDIM + hcol];

    __syncthreads();   // B1: a_lds ready

    // ---- GEMM: 16 MFMA per wave ----
    float4v acc[2][2];   // [ct2][rt]
#pragma unroll
    for (int ct2 = 0; ct2 < 2; ++ct2)
#pragma unroll
      for (int rt = 0; rt < 2; ++rt)
        acc[ct2][rt] = (float4v){0.f, 0.f, 0.f, 0.f};

#pragma unroll
    for (int ks = 0; ks < 4; ++ks) {
      short8 afr[2];
#pragma unroll
      for (int rt = 0; rt < 2; ++rt) {
        int row  = rt * 16 + c;
        int byte = row * 256 + (ks * 32 + g16 * 8) * 2;
        byte ^= (row & 7) << 4;
        afr[rt] = *(const short8*)((const char*)a_lds + byte);
      }
#pragma unroll
      for (int ct2 = 0; ct2 < 2; ++ct2)
#pragma unroll
        for (int rt = 0; rt < 2; ++rt)
          acc[ct2][rt] = __builtin_amdgcn_mfma_f32_16x16x32_bf16(
              afr[rt], bfr[ct2][ks], acc[ct2][rt], 0, 0, 0);
    }

    // ---- epilogue: GLU + skip, DPP 16-lane LN partials, ds_add cross-wave ----
    const int cb = f & 1, nb = cb ^ 1;
    float yv[2][4], sv[2][4], ssv[2][4];
#pragma unroll
    for (int rt = 0; rt < 2; ++rt) {
      float4v x4 = *(const float4v*)&x_lds[f * TOKB + rt * 16 + g16 * 4];
#pragma unroll
      for (int i = 0; i < 4; ++i) {
        float v0 = acc[0][rt][i] + bc0;
        float g0 = acc[1][rt][i] + bc1;
        float y  = fmaf(x4[i], fsk, v0 * sigm_f(g0));
        yv[rt][i]  = y;
        sv[rt][i]  = r16sum(y);
        ssv[rt][i] = r16sum(y * y);
      }
    }
    if (c == 0) {
#pragma unroll
      for (int rt = 0; rt < 2; ++rt)
#pragma unroll
        for (int i = 0; i < 4; ++i) {
          int row = rt * 16 + g16 * 4 + i;
          atomicAdd(&sred[cb][0][row], sv[rt][i]);
          atomicAdd(&sred[cb][1][row], ssv[rt][i]);
        }
    }
    if (tid < 64) sred[nb][tid >> 5][tid & 31] = 0.f;   // zero next buffer

    __syncthreads();   // B2: sred[cb] complete

    // ---- LN finalize + weighted accumulate ----
#pragma unroll
    for (int rt = 0; rt < 2; ++rt) {
      float4v s4  = *(const float4v*)&sred[cb][0][rt * 16 + g16 * 4];
      float4v ss4 = *(const float4v*)&sred[cb][1][rt * 16 + g16 * 4];
      float4v w4  = *(const float4v*)&w_lds[f * TOKB + rt * 16 + g16 * 4];
#pragma unroll
      for (int i = 0; i < 4; ++i) {
        float mean = s4[i] * (1.f / 128.f);
        float var  = ss4[i] * (1.f / 128.f) - mean * mean;
        float rstd = rsqrtf(var + 1e-5f);
        float o2 = (yv[rt][i] - mean) * rstd * lgm + lbt;
        out_acc[rt][i] = fmaf(w4[i], o2, out_acc[rt][i]);
      }
    }
  }

  // ---- store ----
#pragma unroll
  for (int rt = 0; rt < 2; ++rt)
#pragma unroll
    for (int i = 0; i < 4; ++i) {
      int row = t0 + rt * 16 + g16 * 4 + i;
      out[(size_t)row * HDIM + hb + c] = out_acc[rt][i];
    }
}

extern "C" void kernel_launch(void* const* d_in, const int* in_sizes, int n_in,
                              void* d_out, int out_size, void* d_ws, size_t ws_size,
                              hipStream_t stream) {
  const float* x      = (const float*)d_in[0];
  const float* fw1    = (const float*)d_in[1];
  const float* fb1    = (const float*)d_in[2];
  const float* fw2    = (const float*)d_in[3];
  const float* fb2    = (const float*)d_in[4];
  const float* fglu_w = (const float*)d_in[5];
  const float* fglu_b = (const float*)d_in[6];
  const float* fskip  = (const float*)d_in[7];
  const float* fln_g  = (const float*)d_in[8];
  const float* fln_b  = (const float*)d_in[9];
  const float* ww1    = (const float*)d_in[10];
  const float* wb1    = (const float*)d_in[11];
  const float* ww2    = (const float*)d_in[12];
  const float* wb2    = (const float*)d_in[13];
  const float* wglu_w = (const float*)d_in[14];
  const float* wglu_b = (const float*)d_in[15];
  const float* wln_g  = (const float*)d_in[16];
  const float* wln_b  = (const float*)d_in[17];

  float* outp = (float*)d_out;
  float* wout = outp + (size_t)NTOK * HDIM;

  unsigned short* bfrag = (unsigned short*)d_ws;                  // 2 MiB bf16
  float* bcomb = (float*)((char*)d_ws + (size_t)2 * 1024 * 1024); // 32 KiB f32

  k_pw<<<dim3(128 + NTOK / 4), dim3(256), 0, stream>>>(
      x, fw2, fb2, fglu_w, fglu_b, ww1, wb1, ww2, wb2,
      wglu_w, wglu_b, wln_g, wln_b, bfrag, bcomb, wout);
  k_main<<<dim3(NTOK / TOKB), dim3(512), 0, stream>>>(
      x, fw1, fb1, fskip, fln_g, fln_b, bfrag, bcomb, wout, outp);
}